// Round 7
// baseline (127.219 us; speedup 1.0000x reference)
//
#include <hip/hip_runtime.h>
#include <hip/hip_bf16.h>
#include <cstdint>
#include <cstddef>

#define Nn 8
#define Cc 128
#define Oo 128
#define Hh 64
#define Ww 64
#define LL (Hh * Ww)
#define KP 9

typedef __attribute__((ext_vector_type(8))) short short8;
typedef __attribute__((ext_vector_type(4))) float floatx4;
typedef __attribute__((ext_vector_type(4))) int intx4;

#define SGB(m, s, i) __builtin_amdgcn_sched_group_barrier(m, s, i)

__device__ __forceinline__ unsigned short f2bf(float f) {
  unsigned int u = __float_as_uint(f);
  u += 0x7fffu + ((u >> 16) & 1u);   // round-to-nearest-even
  return (unsigned short)(u >> 16);
}

// Fused prep:
//  blocks [0, 512):    x[n][c][h][w] fp32 -> xt[n][h][w][c] bf16
//  blocks [512, 896):  w_b[o][c][3][3] fp32 -> wt2 fragment-contiguous bf16
//  blocks [896, 1024): depth -> packed 27-bit branch-mask codes per pixel
__global__ __launch_bounds__(256) void prep_all(const float* __restrict__ x,
                                                const float* __restrict__ w0,
                                                const float* __restrict__ w1,
                                                const float* __restrict__ w2,
                                                const float* __restrict__ depth,
                                                const float* __restrict__ fx,
                                                unsigned short* __restrict__ xt,
                                                unsigned short* __restrict__ wt2,
                                                unsigned int* __restrict__ codesg) {
  __shared__ float tile[Cc][Ww + 1];
  __shared__ unsigned short wl[Cc * KP];
  const int bid = blockIdx.x;
  const int t = threadIdx.x;
  if (bid < Nn * Hh) {
    const int n = bid >> 6;
    const int h = bid & 63;
    const float* src = x + (size_t)n * Cc * LL + (size_t)h * Ww;
#pragma unroll
    for (int it = 0; it < 8; ++it) {
      const int idx = t + it * 256;          // 0..2047
      const int c = idx >> 4;
      const int w4 = (idx & 15) << 2;
      const float4 v = *reinterpret_cast<const float4*>(src + (size_t)c * LL + w4);
      tile[c][w4 + 0] = v.x; tile[c][w4 + 1] = v.y;
      tile[c][w4 + 2] = v.z; tile[c][w4 + 3] = v.w;
    }
    __syncthreads();
    unsigned short* dst = xt + (size_t)((n * Hh + h) * Ww) * Cc;
#pragma unroll
    for (int it = 0; it < 4; ++it) {
      const int idx = t + it * 256;          // 0..1023
      const int w = idx >> 4;
      const int ch = (idx & 15) << 3;
      short8 v;
#pragma unroll
      for (int q = 0; q < 8; ++q)
        ((unsigned short*)&v)[q] = f2bf(tile[ch + q][w]);
      *reinterpret_cast<short8*>(dst + (size_t)w * Cc + ch) = v;
    }
  } else if (bid < Nn * Hh + 3 * Oo) {
    const int bo = bid - Nn * Hh;            // 0..383
    const int b = bo >> 7;
    const int o = bo & 127;
    const float* w = (b == 0) ? w0 : (b == 1) ? w1 : w2;
    const float* src = w + (size_t)o * Cc * KP;   // contiguous 1152 floats
#pragma unroll
    for (int it = 0; it < 5; ++it) {
      const int idx = t + it * 256;
      if (idx < Cc * KP) wl[idx] = f2bf(src[idx]);   // wl[c*9+kk]
    }
    __syncthreads();
    const int obase = ((o >> 6) & 1) * 2048 + ((o >> 5) & 1) * 1024 +
                      ((o >> 4) & 1) * 512 + (o & 15) * 32;
#pragma unroll
    for (int it = 0; it < 5; ++it) {
      const int idx = t + it * 256;          // 0..1151 = kk*128 + c
      if (idx < Cc * KP) {
        const int kk = idx >> 7;
        const int c = idx & 127;
        const int c0 = c >> 5;
        const int cc = c & 31;
        wt2[(size_t)(b * 36 + kk * 4 + c0) * 4096 + obase + cc] = wl[c * KP + kk];
      }
    }
  } else {
    const int p = (bid - (Nn * Hh + 3 * Oo)) * 256 + t;   // 0..32767
    const int n = p >> 12;
    const int rem = p & 4095;
    const int h = rem >> 6;
    const int w = rem & 63;
    const float center = depth[p];
    const float grid = center / fx[n];       // PIXEL_SIZE*DILATION = 1
    const float half = 0.5f * grid;
    unsigned int packed = 0u;
#pragma unroll
    for (int kk = 0; kk < KP; ++kk) {
      const int hh = h + kk / 3 - 1;
      const int ww = w + kk % 3 - 1;
      float d = 0.0f;
      if (hh >= 0 && hh < Hh && ww >= 0 && ww < Ww) d = depth[(n << 12) + hh * Ww + ww];
      const float valid = (d != 0.0f && center != 0.0f) ? 1.0f : 0.0f;
      const float dm = d * valid;
      unsigned int cb = 0u;
      if (fabsf(dm - (center + grid)) <= half) cb |= 1u;
      float m1v = (fabsf(dm - center) <= half) ? 1.0f : 0.0f;
      m1v = m1v + 1.0f - valid;
      if (m1v > 1.0f) m1v = 1.0f;
      if (m1v > 0.5f) cb |= 2u;
      if (fabsf(dm - (center - grid)) <= half) cb |= 4u;
      packed |= cb << (3 * kk);
    }
    codesg[p] = packed;
  }
}

#define LDXC 132          // pixel stride 66 words; per-32-lane-phase 2-way banks (free)
#define HALO_COLS 66      // w in [-1, 64]
#define HALO_ROWS 4       // h in [h0-1, h0+2]
#define BSTRIDE 147456    // shorts between branch weights in wt2
#define WT2_SHORTS (3 * KP * 4 * 4096)   // 442368
#define PAD_SHORTS 65536                 // tail-prefetch overrun target (never consumed)

__global__ __launch_bounds__(256, 2) void conv_main(
    const unsigned short* __restrict__ xt,
    const unsigned short* __restrict__ wt2,
    const unsigned int* __restrict__ codesg,
    float* __restrict__ out) {
  __shared__ __align__(16) unsigned short Xs[HALO_ROWS * HALO_COLS * LDXC];  // 69696 B

  const int g = blockIdx.x;          // 512 blocks
  const int n = g >> 6;
  const int rem = g & 63;
  const int pb = rem >> 1;           // 0..31  -> row pair
  const int ob1 = rem & 1;           // o-half
  const int h0 = pb * 2;

  const int tid = threadIdx.x;
  const int lane = tid & 63;
  const int wave = tid >> 6;
  const int ln15 = lane & 15;
  const int quad = lane >> 4;
  const int wc = wave & 1;           // o 32-slice within the block's 64
  const int ks = wave >> 1;          // K-split: channels [ks*64, ks*64+64)

  const unsigned short* wfragk =
      wt2 + (size_t)(ob1 * 2048 + wc * 1024 + ln15 * 32 + quad * 8) + (size_t)ks * 8192;
  const char* XsB = reinterpret_cast<const char*>(Xs);

  // per-M-tile A byte bases in LDS (tt=0, dxp=0, chalf=0); +17424 per tt (row step)
  unsigned int abyte[8];
#pragma unroll
  for (int i = 0; i < 8; ++i)
    abyte[i] = (unsigned int)((((i >> 2) * HALO_COLS + (i & 3) * 16 + ln15) * LDXC
                               + quad * 8 + ks * 64) * 2);

  short8 Bb[3][6];   // rotating 3-slot B prefetch (distance 2 steps)
  short8 Aa[2][8];   // rotating 2-slot A prefetch (distance 1 step)

  const unsigned short* bpt = wfragk;

#define LOADB(SLOT, OFFS)                                                       \
  {                                                                             \
    const unsigned short* bp_ = bpt + (OFFS);                                   \
    Bb[SLOT][0] = *reinterpret_cast<const short8*>(bp_);                        \
    Bb[SLOT][1] = *reinterpret_cast<const short8*>(bp_ + 512);                  \
    Bb[SLOT][2] = *reinterpret_cast<const short8*>(bp_ + BSTRIDE);              \
    Bb[SLOT][3] = *reinterpret_cast<const short8*>(bp_ + BSTRIDE + 512);        \
    Bb[SLOT][4] = *reinterpret_cast<const short8*>(bp_ + 2 * BSTRIDE);          \
    Bb[SLOT][5] = *reinterpret_cast<const short8*>(bp_ + 2 * BSTRIDE + 512);    \
  }

#define LOADA(SLOT, IMM)                                                        \
  {                                                                             \
    _Pragma("unroll")                                                           \
    for (int i_ = 0; i_ < 8; ++i_)                                              \
      Aa[SLOT][i_] = *reinterpret_cast<const short8*>(XsB + abyte[i_] + (IMM)); \
  }

  // ---- B prologue loads FIRST: L2 latency overlaps halo staging ----
  LOADB(0, 0)          // sigma=0
  LOADB(1, 4096)       // sigma=1

  // ---- branch-mask codes: direct to registers (precomputed in prep) ----
  unsigned int cd[8];
  {
    const unsigned int* cp = codesg + (n << 12) + h0 * 64 + ln15;
#pragma unroll
    for (int i = 0; i < 8; ++i) cd[i] = cp[i * 16];
  }

  // ---- stage halo tile ONCE: Xs[(hrel*66 + ww+1)][c] = xt[n, h0-1+hrel, ww, c] ----
#pragma unroll
  for (int it = 0; it < 17; ++it) {
    const int idx = tid + it * 256;          // chunks of 8 channels
    if (idx < HALO_ROWS * HALO_COLS * 16) {
      const int ch = (idx & 15) << 3;
      const int pixidx = idx >> 4;           // 0..263
      const int lc = pixidx % HALO_COLS;
      const int hrel = pixidx / HALO_COLS;
      const int hh = h0 - 1 + hrel;
      const int ww = lc - 1;
      short8 v = {0, 0, 0, 0, 0, 0, 0, 0};
      if (hh >= 0 && hh < Hh && ww >= 0 && ww < Ww)
        v = *reinterpret_cast<const short8*>(
            xt + (size_t)((n * Hh + hh) * Ww + ww) * Cc + ch);
      *reinterpret_cast<short8*>(&Xs[pixidx * LDXC + ch]) = v;
    }
  }

  __syncthreads();   // the ONLY pre-epilogue barrier

  const floatx4 zf4 = {0.f, 0.f, 0.f, 0.f};
  floatx4 acc[8][2];
#pragma unroll
  for (int i = 0; i < 8; ++i)
#pragma unroll
    for (int j = 0; j < 2; ++j) acc[i][j] = zf4;

  LOADA(0, 0)          // sigma=0

  // One step U (=0..5): sigma = 6*tt+U, kk = 3*tt + (U>>1), chalf = U&1.
  // Prefetch B(sigma+2) -> slot (U+2)%3, A(sigma+1) -> slot (U+1)&1; all
  // offsets compile-time relative to bpt/abyte. Tail prefetches (sigma>=18)
  // hit the pad region / dead LDS — loaded but never consumed.
#define STEPM(U)                                                                \
  {                                                                             \
    LOADB(((U) + 2) % 3, (((((U) + 2) >> 1) * 4 + ((U) & 1)) * 4096))           \
    LOADA((((U) + 1) & 1),                                                      \
          ((U) == 5 ? 17424 : (((((U) + 1) >> 1) * 132 + (((U) + 1) & 1) * 32) * 2))) \
    const short8* Bp = Bb[(U) % 3];                                             \
    const short8* Ap = Aa[(U) & 1];                                             \
    _Pragma("unroll")                                                           \
    for (int b = 0; b < 3; ++b) {                                               \
      _Pragma("unroll")                                                         \
      for (int i = 0; i < 8; ++i) {                                             \
        const int msk = __builtin_amdgcn_sbfe((int)cd[i], sh + 3 * ((U) >> 1) + b, 1); \
        intx4 a4 = *reinterpret_cast<const intx4*>(&Ap[i]);                     \
        const intx4 m4 = {msk, msk, msk, msk};                                  \
        a4 &= m4;                                                               \
        const short8 af = *reinterpret_cast<const short8*>(&a4);                \
        acc[i][0] = __builtin_amdgcn_mfma_f32_16x16x32_bf16(af, Bp[b * 2 + 0], acc[i][0], 0, 0, 0); \
        acc[i][1] = __builtin_amdgcn_mfma_f32_16x16x32_bf16(af, Bp[b * 2 + 1], acc[i][1], 0, 0, 0); \
      }                                                                         \
    }                                                                           \
    SGB(0x100, 4, 0); SGB(0x008, 8, 0); SGB(0x020, 2, 0); SGB(0x008, 8, 0);     \
    SGB(0x100, 4, 0); SGB(0x008, 8, 0); SGB(0x020, 2, 0); SGB(0x008, 8, 0);     \
    SGB(0x020, 2, 0); SGB(0x008, 16, 0);                                        \
  }

  int sh = 0;   // 9*tt — mask bit base (3*kk = sh + 3*(U>>1))
#pragma unroll 1
  for (int tt = 0; tt < 3; ++tt) {
    STEPM(0) STEPM(1) STEPM(2) STEPM(3) STEPM(4) STEPM(5)
    bpt += 49152;           // next tt's 3 kks: 3*4*4096 shorts
    sh += 9;
#pragma unroll
    for (int i = 0; i < 8; ++i) abyte[i] += 17424;   // +1 halo row (66*132*2 B)
  }
#undef STEPM

  // ---- split-K reduction: ks=1 waves dump partials into LDS (Xs is dead) ----
  __syncthreads();
  float* scratch = reinterpret_cast<float*>(Xs);   // 32 KB used of 69.7 KB
  if (ks == 1) {
#pragma unroll
    for (int i = 0; i < 8; ++i)
#pragma unroll
      for (int j = 0; j < 2; ++j) {
        const int tile = (wc * 16 + i * 2 + j) * 64 + lane;
        *reinterpret_cast<floatx4*>(&scratch[tile * 4]) = acc[i][j];
      }
  }
  __syncthreads();
  if (ks == 0) {
#pragma unroll
    for (int i = 0; i < 8; ++i) {
      const int m = i * 16 + quad * 4;
      const int h = h0 + (m >> 6);
      const int w = m & 63;
#pragma unroll
      for (int j = 0; j < 2; ++j) {
        const int tile = (wc * 16 + i * 2 + j) * 64 + lane;
        const floatx4 other = *reinterpret_cast<const floatx4*>(&scratch[tile * 4]);
        const floatx4 sum = acc[i][j] + other;
        const int o = ob1 * 64 + wc * 32 + j * 16 + ln15;
        float* dst = out + (size_t)(n * Oo + o) * LL + h * Ww + w;
        *reinterpret_cast<floatx4*>(dst) = sum;
      }
    }
  }
}

extern "C" void kernel_launch(void* const* d_in, const int* in_sizes, int n_in,
                              void* d_out, int out_size, void* d_ws, size_t ws_size,
                              hipStream_t stream) {
  const float* x     = (const float*)d_in[0];
  const float* depth = (const float*)d_in[1];
  const float* fx    = (const float*)d_in[2];
  const float* w0    = (const float*)d_in[3];
  const float* w1    = (const float*)d_in[4];
  const float* w2    = (const float*)d_in[5];
  float* out = (float*)d_out;

  // ws layout: xt (8 MB) | wt2 (864 KB) | pad (128 KB, tail-prefetch) | codes (128 KB)
  unsigned short* xt = (unsigned short*)d_ws;
  unsigned short* wt2 = xt + (size_t)Nn * Hh * Ww * Cc;
  unsigned int* codesg = (unsigned int*)(wt2 + (size_t)WT2_SHORTS + PAD_SHORTS);

  prep_all<<<Nn * Hh + 3 * Oo + 128, 256, 0, stream>>>(x, w0, w1, w2, depth, fx, xt, wt2, codesg);
  conv_main<<<512, 256, 0, stream>>>(xt, wt2, codesg, out);
}

// Round 8
// 124.604 us; speedup vs baseline: 1.0210x; 1.0210x over previous
//
#include <hip/hip_runtime.h>
#include <hip/hip_bf16.h>
#include <cstdint>
#include <cstddef>

#define Nn 8
#define Cc 128
#define Oo 128
#define Hh 64
#define Ww 64
#define LL (Hh * Ww)
#define KP 9

typedef __attribute__((ext_vector_type(8))) short short8;
typedef __attribute__((ext_vector_type(4))) float floatx4;
typedef __attribute__((ext_vector_type(4))) int intx4;

#define SGB(m, s, i) __builtin_amdgcn_sched_group_barrier(m, s, i)

__device__ __forceinline__ unsigned short f2bf(float f) {
  unsigned int u = __float_as_uint(f);
  u += 0x7fffu + ((u >> 16) & 1u);   // round-to-nearest-even
  return (unsigned short)(u >> 16);
}

// Fused prep:
//  blocks [0, 512):    x[n][c][h][w] fp32 -> xt[n][h][w][c] bf16
//  blocks [512, 896):  w_b[o][c][3][3] fp32 -> wt2 fragment-contiguous bf16
//  blocks [896, 1024): depth -> packed 27-bit branch-mask codes per pixel
__global__ __launch_bounds__(256) void prep_all(const float* __restrict__ x,
                                                const float* __restrict__ w0,
                                                const float* __restrict__ w1,
                                                const float* __restrict__ w2,
                                                const float* __restrict__ depth,
                                                const float* __restrict__ fx,
                                                unsigned short* __restrict__ xt,
                                                unsigned short* __restrict__ wt2,
                                                unsigned int* __restrict__ codesg) {
  __shared__ float tile[Cc][Ww + 1];
  __shared__ unsigned short wl[Cc * KP];
  const int bid = blockIdx.x;
  const int t = threadIdx.x;
  if (bid < Nn * Hh) {
    const int n = bid >> 6;
    const int h = bid & 63;
    const float* src = x + (size_t)n * Cc * LL + (size_t)h * Ww;
#pragma unroll
    for (int it = 0; it < 8; ++it) {
      const int idx = t + it * 256;          // 0..2047
      const int c = idx >> 4;
      const int w4 = (idx & 15) << 2;
      const float4 v = *reinterpret_cast<const float4*>(src + (size_t)c * LL + w4);
      tile[c][w4 + 0] = v.x; tile[c][w4 + 1] = v.y;
      tile[c][w4 + 2] = v.z; tile[c][w4 + 3] = v.w;
    }
    __syncthreads();
    unsigned short* dst = xt + (size_t)((n * Hh + h) * Ww) * Cc;
#pragma unroll
    for (int it = 0; it < 4; ++it) {
      const int idx = t + it * 256;          // 0..1023
      const int w = idx >> 4;
      const int ch = (idx & 15) << 3;
      short8 v;
#pragma unroll
      for (int q = 0; q < 8; ++q)
        ((unsigned short*)&v)[q] = f2bf(tile[ch + q][w]);
      *reinterpret_cast<short8*>(dst + (size_t)w * Cc + ch) = v;
    }
  } else if (bid < Nn * Hh + 3 * Oo) {
    const int bo = bid - Nn * Hh;            // 0..383
    const int b = bo >> 7;
    const int o = bo & 127;
    const float* w = (b == 0) ? w0 : (b == 1) ? w1 : w2;
    const float* src = w + (size_t)o * Cc * KP;   // contiguous 1152 floats
#pragma unroll
    for (int it = 0; it < 5; ++it) {
      const int idx = t + it * 256;
      if (idx < Cc * KP) wl[idx] = f2bf(src[idx]);   // wl[c*9+kk]
    }
    __syncthreads();
    const int obase = ((o >> 6) & 1) * 2048 + ((o >> 5) & 1) * 1024 +
                      ((o >> 4) & 1) * 512 + (o & 15) * 32;
#pragma unroll
    for (int it = 0; it < 5; ++it) {
      const int idx = t + it * 256;          // 0..1151 = kk*128 + c
      if (idx < Cc * KP) {
        const int kk = idx >> 7;
        const int c = idx & 127;
        const int c0 = c >> 5;
        const int cc = c & 31;
        wt2[(size_t)(b * 36 + kk * 4 + c0) * 4096 + obase + cc] = wl[c * KP + kk];
      }
    }
  } else {
    const int p = (bid - (Nn * Hh + 3 * Oo)) * 256 + t;   // 0..32767
    const int n = p >> 12;
    const int rem = p & 4095;
    const int h = rem >> 6;
    const int w = rem & 63;
    const float center = depth[p];
    const float grid = center / fx[n];       // PIXEL_SIZE*DILATION = 1
    const float half = 0.5f * grid;
    unsigned int packed = 0u;
#pragma unroll
    for (int kk = 0; kk < KP; ++kk) {
      const int hh = h + kk / 3 - 1;
      const int ww = w + kk % 3 - 1;
      float d = 0.0f;
      if (hh >= 0 && hh < Hh && ww >= 0 && ww < Ww) d = depth[(n << 12) + hh * Ww + ww];
      const float valid = (d != 0.0f && center != 0.0f) ? 1.0f : 0.0f;
      const float dm = d * valid;
      unsigned int cb = 0u;
      if (fabsf(dm - (center + grid)) <= half) cb |= 1u;
      float m1v = (fabsf(dm - center) <= half) ? 1.0f : 0.0f;
      m1v = m1v + 1.0f - valid;
      if (m1v > 1.0f) m1v = 1.0f;
      if (m1v > 0.5f) cb |= 2u;
      if (fabsf(dm - (center - grid)) <= half) cb |= 4u;
      packed |= cb << (3 * kk);
    }
    codesg[p] = packed;
  }
}

#define LDXC 132          // pixel stride 66 words -> 2-way bank aliasing (free)
#define HALO_COLS 66      // w in [-1, 64]
#define HALO_ROWS 4       // h in [h0-1, h0+2]
#define NSTEP 18          // per wave: 9 kk x 2 local-c steps (split-K over c0 pairs)
#define BSTRIDE 147456    // shorts between branch weights in wt2
#define WT2_SHORTS (3 * KP * 4 * 4096)   // 442368

// waves_per_eu(2,2): LDS (70 KB) caps at 2 blocks/CU = 2 waves/SIMD anyway;
// telling the backend so lets it allocate up to 256 VGPRs -> the 3-slot B /
// 2-slot A register pipeline survives without spilling (R7: 128 VGPR + spill).
__global__ __launch_bounds__(256) __attribute__((amdgpu_waves_per_eu(2, 2)))
void conv_main(
    const unsigned short* __restrict__ xt,
    const unsigned short* __restrict__ wt2,
    const unsigned int* __restrict__ codesg,
    float* __restrict__ out) {
  __shared__ __align__(16) unsigned short Xs[HALO_ROWS * HALO_COLS * LDXC];  // 69696 B

  const int g = blockIdx.x;          // 512 blocks
  const int n = g >> 6;
  const int rem = g & 63;
  const int pb = rem >> 1;           // 0..31  -> row pair
  const int ob1 = rem & 1;           // o-half
  const int h0 = pb * 2;

  const int tid = threadIdx.x;
  const int lane = tid & 63;
  const int wave = tid >> 6;
  const int ln15 = lane & 15;
  const int quad = lane >> 4;
  const int wc = wave & 1;           // o 32-slice within the block's 64
  const int ks = wave >> 1;          // K-split: channels [ks*64, ks*64+64)

  // fragment-contiguous B base for this wave (ks shifts by 2 c0-chunks)
  const unsigned short* wfragk =
      wt2 + (size_t)(ob1 * 2048 + wc * 1024 + ln15 * 32 + quad * 8) + (size_t)ks * 8192;
  const char* XsB = reinterpret_cast<const char*>(Xs);

  // per-M-tile A byte bases in LDS; all step offsets become 16-bit immediates
  unsigned int abyte[8];
#pragma unroll
  for (int i = 0; i < 8; ++i)
    abyte[i] = (unsigned int)(((((i >> 2) * HALO_COLS + (i & 3) * 16 + ln15) * LDXC)
                               + ks * 64 + quad * 8) * 2);

  short8 Bb[3][6];   // rotating 3-slot B prefetch (distance 2 steps)
  short8 Aa[2][8];   // rotating 2-slot A prefetch (distance 1 step)

#define LOADB(SLOT, S)                                                            \
  {                                                                               \
    const unsigned short* bp = wfragk + (size_t)((((S) >> 1) * 4) + ((S) & 1)) * 4096; \
    Bb[SLOT][0] = *reinterpret_cast<const short8*>(bp);                           \
    Bb[SLOT][1] = *reinterpret_cast<const short8*>(bp + 512);                     \
    Bb[SLOT][2] = *reinterpret_cast<const short8*>(bp + BSTRIDE);                 \
    Bb[SLOT][3] = *reinterpret_cast<const short8*>(bp + BSTRIDE + 512);           \
    Bb[SLOT][4] = *reinterpret_cast<const short8*>(bp + 2 * BSTRIDE);             \
    Bb[SLOT][5] = *reinterpret_cast<const short8*>(bp + 2 * BSTRIDE + 512);       \
  }

#define LOADA(SLOT, S)                                                            \
  {                                                                               \
    const int kkp = (S) >> 1;                                                     \
    const int imm = (kkp / 3) * 17424 + (kkp % 3) * 264 + ((S) & 1) * 64;         \
    _Pragma("unroll")                                                             \
    for (int i_ = 0; i_ < 8; ++i_)                                                \
      Aa[SLOT][i_] = *reinterpret_cast<const short8*>(XsB + abyte[i_] + imm);     \
  }

  // ---- B prologue loads FIRST: L2 latency overlaps halo staging ----
  LOADB(0, 0)
  LOADB(1, 1)

  // ---- branch-mask codes: direct to registers (precomputed in prep) ----
  unsigned int cd[8];
  {
    const unsigned int* cp = codesg + (n << 12) + h0 * 64 + ln15;
#pragma unroll
    for (int i = 0; i < 8; ++i) cd[i] = cp[i * 16];
  }

  // ---- stage halo tile ONCE: Xs[(hrel*66 + ww+1)][c] = xt[n, h0-1+hrel, ww, c] ----
#pragma unroll
  for (int it = 0; it < 17; ++it) {
    const int idx = tid + it * 256;          // chunks of 8 channels
    if (idx < HALO_ROWS * HALO_COLS * 16) {
      const int ch = (idx & 15) << 3;
      const int pixidx = idx >> 4;           // 0..263
      const int lc = pixidx % HALO_COLS;
      const int hrel = pixidx / HALO_COLS;
      const int hh = h0 - 1 + hrel;
      const int ww = lc - 1;
      short8 v = {0, 0, 0, 0, 0, 0, 0, 0};
      if (hh >= 0 && hh < Hh && ww >= 0 && ww < Ww)
        v = *reinterpret_cast<const short8*>(
            xt + (size_t)((n * Hh + hh) * Ww + ww) * Cc + ch);
      *reinterpret_cast<short8*>(&Xs[pixidx * LDXC + ch]) = v;
    }
  }

  __syncthreads();   // the ONLY pre-epilogue barrier

  const floatx4 zf4 = {0.f, 0.f, 0.f, 0.f};
  floatx4 acc[8][2];
#pragma unroll
  for (int i = 0; i < 8; ++i)
#pragma unroll
    for (int j = 0; j < 2; ++j) acc[i][j] = zf4;

  LOADA(0, 0)

  // ---- 18-step fully unrolled pipeline (wave tile M128 x N32 over K/2) ----
  // per step: 6 B VMEM (prefetch dist 2), 8 A ds_reads (dist 1), 48 MFMA.
#pragma unroll
  for (int s = 0; s < NSTEP; ++s) {
    if (s + 2 < NSTEP) LOADB((s + 2) % 3, s + 2)
    if (s + 1 < NSTEP) LOADA((s + 1) & 1, s + 1)
    const int kk = s >> 1;
    const int shift = 3 * kk;
    const short8* B = Bb[s % 3];
    const short8* A = Aa[s & 1];
#pragma unroll
    for (int b = 0; b < 3; ++b) {
#pragma unroll
      for (int i = 0; i < 8; ++i) {
        const int msk = __builtin_amdgcn_sbfe((int)cd[i], shift + b, 1);
        intx4 a4 = *reinterpret_cast<const intx4*>(&A[i]);
        const intx4 m4 = {msk, msk, msk, msk};
        a4 &= m4;
        const short8 af = *reinterpret_cast<const short8*>(&a4);
        acc[i][0] = __builtin_amdgcn_mfma_f32_16x16x32_bf16(af, B[b * 2 + 0], acc[i][0], 0, 0, 0);
        acc[i][1] = __builtin_amdgcn_mfma_f32_16x16x32_bf16(af, B[b * 2 + 1], acc[i][1], 0, 0, 0);
      }
    }
    // schedule template: interleave VMEM/DS with MFMA (VALU unconstrained)
    SGB(0x020, 1, 0); SGB(0x008, 4, 0); SGB(0x100, 1, 0); SGB(0x008, 4, 0);
    SGB(0x020, 1, 0); SGB(0x008, 4, 0); SGB(0x100, 1, 0); SGB(0x008, 4, 0);
    SGB(0x020, 1, 0); SGB(0x008, 4, 0); SGB(0x100, 1, 0); SGB(0x008, 4, 0);
    SGB(0x020, 1, 0); SGB(0x008, 4, 0); SGB(0x100, 1, 0); SGB(0x008, 4, 0);
    SGB(0x020, 1, 0); SGB(0x008, 4, 0); SGB(0x100, 1, 0); SGB(0x008, 4, 0);
    SGB(0x020, 1, 0); SGB(0x008, 4, 0); SGB(0x100, 3, 0); SGB(0x008, 4, 0);
  }

  // ---- split-K reduction: ks=1 waves dump partials into LDS (Xs is dead) ----
  __syncthreads();
  float* scratch = reinterpret_cast<float*>(Xs);   // 32 KB used of 69.7 KB
  if (ks == 1) {
#pragma unroll
    for (int i = 0; i < 8; ++i)
#pragma unroll
      for (int j = 0; j < 2; ++j) {
        const int tile = (wc * 16 + i * 2 + j) * 64 + lane;
        *reinterpret_cast<floatx4*>(&scratch[tile * 4]) = acc[i][j];
      }
  }
  __syncthreads();
  if (ks == 0) {
#pragma unroll
    for (int i = 0; i < 8; ++i) {
      const int m = i * 16 + quad * 4;
      const int h = h0 + (m >> 6);
      const int w = m & 63;
#pragma unroll
      for (int j = 0; j < 2; ++j) {
        const int tile = (wc * 16 + i * 2 + j) * 64 + lane;
        const floatx4 other = *reinterpret_cast<const floatx4*>(&scratch[tile * 4]);
        const floatx4 sum = acc[i][j] + other;
        const int o = ob1 * 64 + wc * 32 + j * 16 + ln15;
        float* dst = out + (size_t)(n * Oo + o) * LL + h * Ww + w;
        *reinterpret_cast<floatx4*>(dst) = sum;
      }
    }
  }
}

extern "C" void kernel_launch(void* const* d_in, const int* in_sizes, int n_in,
                              void* d_out, int out_size, void* d_ws, size_t ws_size,
                              hipStream_t stream) {
  const float* x     = (const float*)d_in[0];
  const float* depth = (const float*)d_in[1];
  const float* fx    = (const float*)d_in[2];
  const float* w0    = (const float*)d_in[3];
  const float* w1    = (const float*)d_in[4];
  const float* w2    = (const float*)d_in[5];
  float* out = (float*)d_out;

  // ws layout: xt (8 MB) | wt2 (864 KB) | codes (128 KB)
  unsigned short* xt = (unsigned short*)d_ws;
  unsigned short* wt2 = xt + (size_t)Nn * Hh * Ww * Cc;
  unsigned int* codesg = (unsigned int*)(wt2 + (size_t)WT2_SHORTS);

  prep_all<<<Nn * Hh + 3 * Oo + 128, 256, 0, stream>>>(x, w0, w1, w2, depth, fx, xt, wt2, codesg);
  conv_main<<<512, 256, 0, stream>>>(xt, wt2, codesg, out);
}

// Round 9
// 111.206 us; speedup vs baseline: 1.1440x; 1.1205x over previous
//
#include <hip/hip_runtime.h>
#include <hip/hip_bf16.h>
#include <cstdint>
#include <cstddef>

#define Nn 8
#define Cc 128
#define Oo 128
#define Hh 64
#define Ww 64
#define LL (Hh * Ww)
#define KP 9

#define XROW 8448              // 66*128 shorts per padded row
#define XTP_N 557568           // 66*66*128 shorts per image
#define WT2_SHORTS (3 * KP * 4 * 4096)   // 442368
#define SLAB 20480             // bytes per pipeline slab (A 8192 + B 12288)

typedef __attribute__((ext_vector_type(8))) short short8;
typedef __attribute__((ext_vector_type(4))) float floatx4;
typedef __attribute__((ext_vector_type(4))) int intx4;

__device__ __forceinline__ unsigned short f2bf(float f) {
  unsigned int u = __float_as_uint(f);
  u += 0x7fffu + ((u >> 16) & 1u);   // round-to-nearest-even
  return (unsigned short)(u >> 16);
}

__device__ __forceinline__ void gl_lds16(const void* g, void* l) {
  __builtin_amdgcn_global_load_lds(
      (const __attribute__((address_space(1))) unsigned int*)g,
      (__attribute__((address_space(3))) unsigned int*)l, 16, 0, 0);
}

// Fused prep:
//  [0,512):    x[n][c][h][w] fp32 -> xtp[n][1+h][1+w][c] bf16 (zero-padded halo)
//  [512,896):  w_b[o][c][3][3] fp32 -> wt2 fragment-contiguous bf16
//  [896,1024): depth -> packed 27-bit branch-mask codes per pixel
//  [1024,1040): zero xtp borders (ws is 0xAA-poisoned before every call)
__global__ __launch_bounds__(256) void prep_all(const float* __restrict__ x,
                                                const float* __restrict__ w0,
                                                const float* __restrict__ w1,
                                                const float* __restrict__ w2,
                                                const float* __restrict__ depth,
                                                const float* __restrict__ fx,
                                                unsigned short* __restrict__ xtp,
                                                unsigned short* __restrict__ wt2,
                                                unsigned int* __restrict__ codesg) {
  __shared__ float tile[Cc][Ww + 1];
  __shared__ unsigned short wl[Cc * KP];
  const int bid = blockIdx.x;
  const int t = threadIdx.x;
  if (bid < Nn * Hh) {
    const int n = bid >> 6;
    const int h = bid & 63;
    const float* src = x + (size_t)n * Cc * LL + (size_t)h * Ww;
#pragma unroll
    for (int it = 0; it < 8; ++it) {
      const int idx = t + it * 256;          // 0..2047
      const int c = idx >> 4;
      const int w4 = (idx & 15) << 2;
      const float4 v = *reinterpret_cast<const float4*>(src + (size_t)c * LL + w4);
      tile[c][w4 + 0] = v.x; tile[c][w4 + 1] = v.y;
      tile[c][w4 + 2] = v.z; tile[c][w4 + 3] = v.w;
    }
    __syncthreads();
    unsigned short* dst = xtp + (size_t)n * XTP_N + (size_t)(h + 1) * XROW + 128;
#pragma unroll
    for (int it = 0; it < 4; ++it) {
      const int idx = t + it * 256;          // 0..1023
      const int w = idx >> 4;
      const int ch = (idx & 15) << 3;
      short8 v;
#pragma unroll
      for (int q = 0; q < 8; ++q)
        ((unsigned short*)&v)[q] = f2bf(tile[ch + q][w]);
      *reinterpret_cast<short8*>(dst + (size_t)w * Cc + ch) = v;
    }
  } else if (bid < Nn * Hh + 3 * Oo) {
    const int bo = bid - Nn * Hh;            // 0..383
    const int b = bo >> 7;
    const int o = bo & 127;
    const float* w = (b == 0) ? w0 : (b == 1) ? w1 : w2;
    const float* src = w + (size_t)o * Cc * KP;   // contiguous 1152 floats
#pragma unroll
    for (int it = 0; it < 5; ++it) {
      const int idx = t + it * 256;
      if (idx < Cc * KP) wl[idx] = f2bf(src[idx]);   // wl[c*9+kk]
    }
    __syncthreads();
    const int obase = ((o >> 6) & 1) * 2048 + ((o >> 5) & 1) * 1024 +
                      ((o >> 4) & 1) * 512 + (o & 15) * 32;
#pragma unroll
    for (int it = 0; it < 5; ++it) {
      const int idx = t + it * 256;          // 0..1151 = kk*128 + c
      if (idx < Cc * KP) {
        const int kk = idx >> 7;
        const int c = idx & 127;
        wt2[(size_t)(b * 36 + kk * 4 + (c >> 5)) * 4096 + obase + (c & 31)] = wl[c * KP + kk];
      }
    }
  } else if (bid < Nn * Hh + 3 * Oo + 128) {
    const int p = (bid - (Nn * Hh + 3 * Oo)) * 256 + t;   // 0..32767
    const int n = p >> 12;
    const int rem = p & 4095;
    const int h = rem >> 6;
    const int w = rem & 63;
    const float center = depth[p];
    const float grid = center / fx[n];       // PIXEL_SIZE*DILATION = 1
    const float half = 0.5f * grid;
    unsigned int packed = 0u;
#pragma unroll
    for (int kk = 0; kk < KP; ++kk) {
      const int hh = h + kk / 3 - 1;
      const int ww = w + kk % 3 - 1;
      float d = 0.0f;
      if (hh >= 0 && hh < Hh && ww >= 0 && ww < Ww) d = depth[(n << 12) + hh * Ww + ww];
      const float valid = (d != 0.0f && center != 0.0f) ? 1.0f : 0.0f;
      const float dm = d * valid;
      unsigned int cb = 0u;
      if (fabsf(dm - (center + grid)) <= half) cb |= 1u;
      float m1v = (fabsf(dm - center) <= half) ? 1.0f : 0.0f;
      m1v = m1v + 1.0f - valid;
      if (m1v > 1.0f) m1v = 1.0f;
      if (m1v > 0.5f) cb |= 2u;
      if (fabsf(dm - (center - grid)) <= half) cb |= 4u;
      packed |= cb << (3 * kk);
    }
    codesg[p] = packed;
  } else {
    // zero xtp borders
    const int b = bid - (Nn * Hh + 3 * Oo + 128);   // 0..15
    const int n = b >> 1;
    unsigned short* base = xtp + (size_t)n * XTP_N;
    const short8 z = {0, 0, 0, 0, 0, 0, 0, 0};
    if ((b & 1) == 0) {
      // rows 0 and 65, all 66 cols: 2*66*128/8 = 2112 short8
#pragma unroll
      for (int it = 0; it < 9; ++it) {
        const int idx = t + it * 256;
        if (idx < 2112) {
          const int r = (idx < 1056) ? 0 : 65;
          const int off = (idx % 1056) * 8;
          *reinterpret_cast<short8*>(base + (size_t)r * XROW + off) = z;
        }
      }
    } else {
      // cols 0 and 65, rows 1..64: 2*64*128/8 = 2048 short8
#pragma unroll
      for (int it = 0; it < 8; ++it) {
        const int idx = t + it * 256;      // 0..2047
        const int c = (idx < 1024) ? 0 : 65;
        const int k = idx & 1023;
        const int row = 1 + (k >> 4);
        const int ch = (k & 15) * 8;
        *reinterpret_cast<short8*>(base + (size_t)row * XROW + (size_t)c * 128 + ch) = z;
      }
    }
  }
}

// Triple-buffered DMA pipeline GEMM:
//  block = M128 (2 image rows) x N64 (o-half), 4 waves (mh x wc), wave M64xN32, full K.
//  36 steps (kk 9 x c0 4). Per step: stage(s+2) via global_load_lds -> slab[(s+2)%3],
//  consume slab[s%3], ONE __syncthreads. vmcnt(0) drain at the barrier waits only on
//  loads issued this iteration (~900 cy earlier) -> drain-free steady state.
__global__ __launch_bounds__(256, 2) void conv_main(
    const unsigned short* __restrict__ xtp,
    const unsigned short* __restrict__ wt2,
    const unsigned int* __restrict__ codesg,
    float* __restrict__ out) {
  __shared__ __align__(16) char slabs[3 * SLAB];   // 61440 B

  const int g = blockIdx.x;          // 512 blocks
  const int n = g >> 6;
  const int rem = g & 63;
  const int pb = rem >> 1;           // 0..31  -> row pair
  const int ob1 = rem & 1;           // o-half
  const int h0 = pb * 2;

  const int tid = threadIdx.x;
  const int lane = tid & 63;
  const int wv = tid >> 6;
  const int ln15 = lane & 15;
  const int quad = lane >> 4;
  const int mh = wv >> 1;            // m-half (0/1)
  const int wc = wv & 1;             // o 32-slice

  // ---- hoisted per-lane staging gather bases ----
  // A issues: a = wv*2 + t; lane covers pix = a*16 + (lane>>2), col = lane&3.
  const unsigned short* gA[2];
#pragma unroll
  for (int t = 0; t < 2; ++t) {
    const int a = wv * 2 + t;
    const int pix = a * 16 + (lane >> 2);
    const int col = lane & 3;
    const int q = (col - pix - (pix >> 2)) & 3;          // inverse xor-col swizzle
    gA[t] = xtp + (size_t)n * XTP_N
            + (size_t)((h0 + (pix >> 6)) * 66 + (pix & 63)) * 128 + q * 8;
  }
  // B issues: bI = wv*3 + t; bb = bI>>2, q4 = bI&3; lane covers o = q4*16 + (lane>>2).
  const unsigned short* gB[3];
  int ldsB[3];
#pragma unroll
  for (int t = 0; t < 3; ++t) {
    const int bI = wv * 3 + t;
    const int bb = bI >> 2, q4 = bI & 3;
    const int o = q4 * 16 + (lane >> 2);
    const int col = lane & 3;
    const int q = (col - o - (o >> 2)) & 3;
    gB[t] = wt2 + (size_t)bb * (KP * 4 * 4096) + ob1 * 2048 + o * 32 + q * 8;
    ldsB[t] = 8192 + bb * 4096 + q4 * 1024;
  }

  // ---- hoisted per-lane fragment-read offsets (within a slab) ----
  int aRd[4];
#pragma unroll
  for (int i = 0; i < 4; ++i) {
    const int p = mh * 64 + i * 16 + ln15;
    const int col = (quad + p + (p >> 2)) & 3;
    aRd[i] = p * 64 + col * 16;
  }
  int bRd[3][2];
#pragma unroll
  for (int bb = 0; bb < 3; ++bb)
#pragma unroll
    for (int j = 0; j < 2; ++j) {
      const int o = wc * 32 + j * 16 + ln15;
      const int col = (quad + o + (o >> 2)) & 3;
      bRd[bb][j] = 8192 + bb * 4096 + o * 64 + col * 16;
    }

  // stage step sigma into slab at byte offset stgOff
  auto stage = [&](int sigma, int stgOff) {
    const int kk2 = sigma >> 2;
    const int c02 = sigma & 3;
    const int dyp = (kk2 * 11) >> 5;                 // kk2 / 3
    const int dxp = kk2 - 3 * dyp;
    const int aoff = ((dyp * 66 + dxp) * 128 + c02 * 32) * 2;   // bytes into xtp row block
#pragma unroll
    for (int t = 0; t < 2; ++t)
      gl_lds16((const char*)gA[t] + aoff, slabs + stgOff + (wv * 2 + t) * 1024);
    const int boff = sigma * 8192;                   // ((kk2*4+c02)*4096) shorts * 2B
#pragma unroll
    for (int t = 0; t < 3; ++t)
      gl_lds16((const char*)gB[t] + boff, slabs + stgOff + ldsB[t]);
  };

  // ---- branch-mask codes (precomputed in prep) ----
  unsigned int cd[4];
  {
    const unsigned int* cp = codesg + (n << 12) + h0 * 64 + mh * 64 + ln15;
#pragma unroll
    for (int i = 0; i < 4; ++i) cd[i] = cp[i * 16];
  }

  const floatx4 zf4 = {0.f, 0.f, 0.f, 0.f};
  floatx4 acc[4][2];
#pragma unroll
  for (int i = 0; i < 4; ++i) {
    acc[i][0] = zf4; acc[i][1] = zf4;
  }

  // ---- prologue: stage steps 0,1; single drain ----
  stage(0, 0);
  stage(1, SLAB);
  __syncthreads();

  int cons = 0;                       // byte offset of consume slab
#pragma unroll 1
  for (int s = 0; s < 36; ++s) {
    int stg = cons + 2 * SLAB; if (stg >= 3 * SLAB) stg -= 3 * SLAB;
    if (s + 2 < 36) stage(s + 2, stg);     // issue DMA FIRST (latency overlaps compute)

    const char* slabC = slabs + cons;
    short8 Af[4], Bf[3][2];
#pragma unroll
    for (int i = 0; i < 4; ++i)
      Af[i] = *reinterpret_cast<const short8*>(slabC + aRd[i]);
#pragma unroll
    for (int bb = 0; bb < 3; ++bb)
#pragma unroll
      for (int j = 0; j < 2; ++j)
        Bf[bb][j] = *reinterpret_cast<const short8*>(slabC + bRd[bb][j]);

    const int sh3 = 3 * (s >> 2);     // 3*kk
#pragma unroll
    for (int bb = 0; bb < 3; ++bb) {
#pragma unroll
      for (int i = 0; i < 4; ++i) {
        const int msk = __builtin_amdgcn_sbfe((int)cd[i], sh3 + bb, 1);
        intx4 a4 = *reinterpret_cast<const intx4*>(&Af[i]);
        const intx4 m4 = {msk, msk, msk, msk};
        a4 &= m4;
        const short8 af = *reinterpret_cast<const short8*>(&a4);
        acc[i][0] = __builtin_amdgcn_mfma_f32_16x16x32_bf16(af, Bf[bb][0], acc[i][0], 0, 0, 0);
        acc[i][1] = __builtin_amdgcn_mfma_f32_16x16x32_bf16(af, Bf[bb][1], acc[i][1], 0, 0, 0);
      }
    }

    __syncthreads();                  // drains this iter's DMA; guards slab rotation
    cons += SLAB; if (cons == 3 * SLAB) cons = 0;
  }

  // ---- epilogue: D row = m (quad*4+reg), col = o (lane&15) ----
#pragma unroll
  for (int i = 0; i < 4; ++i) {
    const int m = mh * 64 + i * 16 + quad * 4;
    const int h = h0 + (m >> 6);
    const int w = m & 63;
#pragma unroll
    for (int j = 0; j < 2; ++j) {
      const int o = ob1 * 64 + wc * 32 + j * 16 + ln15;
      float* dst = out + (size_t)(n * Oo + o) * LL + h * Ww + w;
      *reinterpret_cast<floatx4*>(dst) = acc[i][j];
    }
  }
}

extern "C" void kernel_launch(void* const* d_in, const int* in_sizes, int n_in,
                              void* d_out, int out_size, void* d_ws, size_t ws_size,
                              hipStream_t stream) {
  const float* x     = (const float*)d_in[0];
  const float* depth = (const float*)d_in[1];
  const float* fx    = (const float*)d_in[2];
  const float* w0    = (const float*)d_in[3];
  const float* w1    = (const float*)d_in[4];
  const float* w2    = (const float*)d_in[5];
  float* out = (float*)d_out;

  // ws layout: xtp (8.92 MB padded) | wt2 (864 KB) | codes (128 KB)
  unsigned short* xtp = (unsigned short*)d_ws;
  unsigned short* wt2 = xtp + (size_t)Nn * XTP_N;
  unsigned int* codesg = (unsigned int*)(wt2 + (size_t)WT2_SHORTS);

  prep_all<<<Nn * Hh + 3 * Oo + 128 + 16, 256, 0, stream>>>(x, w0, w1, w2, depth, fx,
                                                            xtp, wt2, codesg);
  conv_main<<<512, 256, 0, stream>>>(xtp, wt2, codesg, out);
}